// Round 7
// baseline (1049.977 us; speedup 1.0000x reference)
//
#include <hip/hip_runtime.h>
#include <hip/hip_bf16.h>

typedef __bf16 bf16x8 __attribute__((ext_vector_type(8)));
typedef __bf16 bf16x4 __attribute__((ext_vector_type(4)));
typedef float  f32x4  __attribute__((ext_vector_type(4)));

#define MFMA(a,b,c) __builtin_amdgcn_mfma_f32_16x16x32_bf16((a),(b),(c),0,0,0)

// problem constants
#define NN_  42
#define E_   41
#define FB_  4096
#define SCALE_ 0.17677669529663687f  // 1/sqrt(32)

// ws layout, element offsets into __bf16* ws (native [out][in] row-major == MFMA A-operand rows)
#define WB_WIN  0         // [128][32]
#define WB_QKV  4096      // [L][384][128]
#define WB_AO   102400    // [L][128][128]
#define WB_FF1  135168    // [L][256][128]
#define WB_FF2  200704    // [L][128][256]
#define WB_WOUT 266240    // [128][5376]
#define WB_X    954368    // [4096][5376] staged x_final (bf16)
#define PREP_N  954368

// smem byte offsets
#define SM_K    0         // K [48][136] bf16 = 13056
#define SM_V    13056     // V^T [128][72] bf16 = 18432 (pad cols 48..63 re-zeroed EVERY layer)
#define SM_ADJ  31488     // int[123]
#define SM_DEP  31984     // int[48]
#define SM_SZ   32176
// aliases over SM_K..: posf f32[48][132] (pre-layer-0 only); hl per-wave slabs
// [16][264] bf16 = 8448 B/wave x3 = 25344 (FF section only; guarded by layer-top +
// post-attention barriers)

// ---------------- weight cast to bf16 ----------------
__global__ void prep_bf16(const float* __restrict__ W_in, const float* __restrict__ qkv_w,
                          const float* __restrict__ ao_w, const float* __restrict__ ff1_w,
                          const float* __restrict__ ff2_w, const float* __restrict__ W_out,
                          __bf16* __restrict__ wb) {
  int i = blockIdx.x * 256 + threadIdx.x;
  float v;
  if      (i < 4096)   v = W_in[i];
  else if (i < 102400) v = qkv_w[i - 4096];
  else if (i < 135168) v = ao_w[i - 102400];
  else if (i < 200704) v = ff1_w[i - 135168];
  else if (i < 266240) v = ff2_w[i - 200704];
  else if (i < 954368) v = W_out[i - 266240];
  else return;
  wb[i] = (__bf16)v;
}

__device__ __forceinline__ bf16x8 ld8(const __bf16* p) { return *(const bf16x8*)p; }

__device__ __forceinline__ int pack2(float a, float b) {
  union { __bf16 h[2]; int i; } u;
  u.h[0] = (__bf16)a; u.h[1] = (__bf16)b;
  return u.i;
}

// C-frag pair (k on rows: lo tile k 0..15, hi tile k 16..31; n on c16, packed reg-pairs as
// dwords lo0/lo1/hi0/hi1) -> B-frag (n=c16, k=quad*8+j).
__device__ __forceinline__ bf16x8 trans2(int lo0, int lo1, int hi0, int hi1, int c16, int quad) {
  int s0 = ((quad & 1) * 2) * 16 + c16, s1 = s0 + 16;
  int a0 = __shfl(lo0, s0), a1 = __shfl(lo1, s0), a2 = __shfl(lo0, s1), a3 = __shfl(lo1, s1);
  int b0 = __shfl(hi0, s0), b1 = __shfl(hi1, s0), b2 = __shfl(hi0, s1), b3 = __shfl(hi1, s1);
  union { int i[4]; bf16x8 v; } u;
  bool hi = quad > 1;
  u.i[0] = hi ? b0 : a0; u.i[1] = hi ? b1 : a1;
  u.i[2] = hi ? b2 : a2; u.i[3] = hi ? b3 : a3;
  return u.v;
}

// wave-private LayerNorm over x^T frags (feature dim on mt/quad/r; node on c16)
__device__ __forceinline__ void ln_reg(float (&res)[8][4], const float* __restrict__ g,
                                       const float* __restrict__ b, int quad) {
  float s = 0.f, ss = 0.f;
#pragma unroll
  for (int mt = 0; mt < 8; ++mt)
#pragma unroll
    for (int r = 0; r < 4; ++r) { float v = res[mt][r]; s += v; ss += v * v; }
  s += __shfl_xor(s, 16); ss += __shfl_xor(ss, 16);
  s += __shfl_xor(s, 32); ss += __shfl_xor(ss, 32);
  float mu = s * 0.0078125f;
  float var = fmaxf(ss * 0.0078125f - mu * mu, 0.f);
  float rs = rsqrtf(var + 1e-5f);
#pragma unroll
  for (int mt = 0; mt < 8; ++mt) {
    f32x4 g4 = *(const f32x4*)(g + mt * 16 + quad * 4);
    f32x4 b4 = *(const f32x4*)(b + mt * 16 + quad * 4);
#pragma unroll
    for (int r = 0; r < 4; ++r) res[mt][r] = (res[mt][r] - mu) * rs * g4[r] + b4[r];
  }
}

// ---------------- per-tree fused encoder: node-partitioned, register-resident x^T ----------------
// (192,2): VGPR cap 256. R5's (192,3) spilled (725 MB scratch); R6 still spilled 157 MB at the
// 128-reg plateau -> this revision removes ~80 regs of pressure (hdw->LDS slab, ot dropped).
__global__ __launch_bounds__(192, 2) void tree_enc(
    const float* __restrict__ forest, const int* __restrict__ adjacency,
    const int* __restrict__ node_order, const float* __restrict__ b_in,
    const float* __restrict__ qkv_b, const float* __restrict__ ao_b,
    const float* __restrict__ ff1_b, const float* __restrict__ ff2_b,
    const float* __restrict__ ln1_g, const float* __restrict__ ln1_b,
    const float* __restrict__ ln2_g, const float* __restrict__ ln2_b,
    const __bf16* __restrict__ wb, __bf16* __restrict__ Xg) {
  const int f = blockIdx.x, tid = threadIdx.x;
  const int lane = tid & 63, w = tid >> 6, c16 = lane & 15, quad = lane >> 4;
  const int node = w * 16 + c16;               // this lane's node (B-operand n / C col)
  const int nclamp = node < NN_ ? node : NN_ - 1;

  __shared__ alignas(16) unsigned char smem[SM_SZ];
  __bf16* Kl = (__bf16*)(smem + SM_K);         // [48][136]: K[key][feat]
  __bf16* Vl = (__bf16*)(smem + SM_V);         // [128][72]: V^T[d][key]
  float*  posf = (float*)(smem + SM_K);        // [48][132] f32 (aliases; pre-layer-0 only)
  __bf16* hw   = (__bf16*)(smem + (size_t)w * 8448);  // per-wave FF-hidden slab [16][264]
  int*    adj_s = (int*)(smem + SM_ADJ);
  int*    dep_s = (int*)(smem + SM_DEP);

  // ---- init: zero pos, load adjacency, depths ----
  for (int i = tid; i < 48 * 132; i += 192) posf[i] = 0.f;
  if (tid < E_ * 3) adj_s[tid] = adjacency[f * (E_ * 3) + tid];
  if (w == 1) {
    int v = (lane < NN_) ? node_order[f * NN_ + lane] : 0;
    int mx = v;
#pragma unroll
    for (int m = 1; m < 64; m <<= 1) mx = max(mx, __shfl_xor(mx, m));
    if (lane < 48) dep_s[lane] = (lane < NN_) ? (mx - v) : 0;
  }
  __syncthreads();  // B1

  // ---- embed MFMA: x0^T = W_in @ forest_own^T (+ bias); B = forest row of own node ----
  float res[8][4];
  {
    const float* fr = forest + ((size_t)f * NN_ + nclamp) * 32 + quad * 8;
    f32x4 fa = *(const f32x4*)fr;
    f32x4 fb = *(const f32x4*)(fr + 4);
    union { int i[4]; bf16x8 v; } Bf;
    Bf.i[0] = pack2(fa[0], fa[1]); Bf.i[1] = pack2(fa[2], fa[3]);
    Bf.i[2] = pack2(fb[0], fb[1]); Bf.i[3] = pack2(fb[2], fb[3]);
#pragma unroll
    for (int mt = 0; mt < 8; ++mt) {
      bf16x8 a = ld8(wb + WB_WIN + (mt * 16 + c16) * 32 + quad * 8);
      f32x4 z{0, 0, 0, 0};
      f32x4 c = MFMA(a, Bf.v, z);
      f32x4 bi = *(const f32x4*)(b_in + mt * 16 + quad * 4);
#pragma unroll
      for (int r = 0; r < 4; ++r) res[mt][r] = c[r] + bi[r];
    }
  }
  // positional-encoding walk (wave 0; parent idx < child idx in edge order)
  if (w == 0) {
    for (int e = 0; e < E_; ++e) {
      int p = adj_s[e * 3], c = adj_s[e * 3 + 1], s = adj_s[e * 3 + 2];
      if (p >= 0 && c >= 0) {
        int pl = p - f * NN_, cl = c - f * NN_;
        int si = s + 1; si = si < 0 ? 0 : (si > 2 ? 2 : si);
        int idx = dep_s[pl] * 3 + si;
        float a0 = (lane == idx) ? 1.f : 0.f;
        float a1 = (lane + 64 == idx) ? 1.f : 0.f;
        posf[cl * 132 + lane] = posf[pl * 132 + lane] + a0;
        posf[cl * 132 + 64 + lane] = posf[pl * 132 + 64 + lane] + a1;
      }
    }
  }
  __syncthreads();  // B2

  // add pos (read own node's row)
#pragma unroll
  for (int mt = 0; mt < 8; ++mt) {
    f32x4 pv = *(const f32x4*)(posf + node * 132 + mt * 16 + quad * 4);
#pragma unroll
    for (int r = 0; r < 4; ++r) res[mt][r] += pv[r];
  }
  int xdw[8][2];
#pragma unroll
  for (int mt = 0; mt < 8; ++mt) {
    xdw[mt][0] = pack2(res[mt][0], res[mt][1]);
    xdw[mt][1] = pack2(res[mt][2], res[mt][3]);
  }

  // ---- encoder layers ----
  for (int l = 0; l < 2; ++l) {
    __syncthreads();  // layer top: prior readers of pos / K,V / hl done before overwrite

    // zero V^T key-columns 48..63 EVERY layer (hl clobbers rows 0..87 of Vl during FF;
    // PV's second MFMA reads them with P==0 and NaN*0=NaN — R4 lesson).
    {
      int* vz = (int*)Vl;
      for (int i = tid; i < 1024; i += 192) {
        int row = i >> 3, dc = i & 7;
        vz[row * 36 + 24 + dc] = 0;  // bf16 cols 48..63 of each of 128 rows
      }
    }

    const __bf16* Wq = wb + WB_QKV + l * 384 * 128;
    bf16x8 Bx[4];
#pragma unroll
    for (int ks = 0; ks < 4; ++ks)
      Bx[ks] = trans2(xdw[2 * ks][0], xdw[2 * ks][1], xdw[2 * ks + 1][0], xdw[2 * ks + 1][1], c16, quad);

    int qdw[8][2];
    // q-part (rows 0..127): keep in regs (packed)
#pragma unroll
    for (int mt = 0; mt < 8; ++mt) {
      f32x4 acc{0, 0, 0, 0};
#pragma unroll
      for (int ks = 0; ks < 4; ++ks)
        acc = MFMA(ld8(Wq + (mt * 16 + c16) * 128 + ks * 32 + quad * 8), Bx[ks], acc);
      f32x4 bi = *(const f32x4*)(qkv_b + l * 384 + mt * 16 + quad * 4);
      qdw[mt][0] = pack2(acc[0] + bi[0], acc[1] + bi[1]);
      qdw[mt][1] = pack2(acc[2] + bi[2], acc[3] + bi[3]);
    }
    // k-part (rows 128..255) -> K LDS [key][feat]
#pragma unroll
    for (int mt = 0; mt < 8; ++mt) {
      f32x4 acc{0, 0, 0, 0};
#pragma unroll
      for (int ks = 0; ks < 4; ++ks)
        acc = MFMA(ld8(Wq + (128 + mt * 16 + c16) * 128 + ks * 32 + quad * 8), Bx[ks], acc);
      f32x4 bi = *(const f32x4*)(qkv_b + l * 384 + 128 + mt * 16 + quad * 4);
#pragma unroll
      for (int r = 0; r < 4; ++r)
        Kl[node * 136 + mt * 16 + quad * 4 + r] = (__bf16)(acc[r] + bi[r]);
    }
    // v-part (rows 256..383) -> V^T LDS [d][key]
#pragma unroll
    for (int mt = 0; mt < 8; ++mt) {
      f32x4 acc{0, 0, 0, 0};
#pragma unroll
      for (int ks = 0; ks < 4; ++ks)
        acc = MFMA(ld8(Wq + (256 + mt * 16 + c16) * 128 + ks * 32 + quad * 8), Bx[ks], acc);
      f32x4 bi = *(const f32x4*)(qkv_b + l * 384 + 256 + mt * 16 + quad * 4);
#pragma unroll
      for (int r = 0; r < 4; ++r)
        Vl[(mt * 16 + quad * 4 + r) * 72 + node] = (__bf16)(acc[r] + bi[r]);
    }
    __syncthreads();  // K,V visible

    // === attention: all 4 heads, wave-private; PV packs straight to odw (no ot array) ===
    int odw[8][2];
#pragma unroll
    for (int h = 0; h < 4; ++h) {
      bf16x8 Bq = trans2(qdw[2 * h][0], qdw[2 * h][1], qdw[2 * h + 1][0], qdw[2 * h + 1][1], c16, quad);
      f32x4 st[3];
#pragma unroll
      for (int mt = 0; mt < 3; ++mt) {
        f32x4 z{0, 0, 0, 0};
        st[mt] = MFMA(ld8(Kl + (mt * 16 + c16) * 136 + h * 32 + quad * 8), Bq, z);
      }
      float mx = -3.0e38f;
#pragma unroll
      for (int mt = 0; mt < 3; ++mt)
#pragma unroll
        for (int r = 0; r < 4; ++r) {
          float v = st[mt][r] * SCALE_;
          bool valid = (mt < 2) || (quad * 4 + r < 10);  // key < 42
          st[mt][r] = valid ? v : -3.0e38f;
          mx = fmaxf(mx, st[mt][r]);
        }
      mx = fmaxf(mx, __shfl_xor(mx, 16));
      mx = fmaxf(mx, __shfl_xor(mx, 32));
      float sm = 0.f, ev[3][4];
#pragma unroll
      for (int mt = 0; mt < 3; ++mt)
#pragma unroll
        for (int r = 0; r < 4; ++r) { float e = __expf(st[mt][r] - mx); ev[mt][r] = e; sm += e; }
      sm += __shfl_xor(sm, 16);
      sm += __shfl_xor(sm, 32);
      float inv = 1.f / sm;
      int dwp[3][2];
#pragma unroll
      for (int mt = 0; mt < 3; ++mt) {
        dwp[mt][0] = pack2(ev[mt][0] * inv, ev[mt][1] * inv);
        dwp[mt][1] = pack2(ev[mt][2] * inv, ev[mt][3] * inv);
      }
      bf16x8 Bp0 = trans2(dwp[0][0], dwp[0][1], dwp[1][0], dwp[1][1], c16, quad);
      bf16x8 Bp1 = trans2(dwp[2][0], dwp[2][1], 0, 0, c16, quad);
#pragma unroll
      for (int dt = 0; dt < 2; ++dt) {
        f32x4 acc{0, 0, 0, 0};
        acc = MFMA(ld8(Vl + (h * 32 + dt * 16 + c16) * 72 + quad * 8), Bp0, acc);
        acc = MFMA(ld8(Vl + (h * 32 + dt * 16 + c16) * 72 + 32 + quad * 8), Bp1, acc);
        odw[h * 2 + dt][0] = pack2(acc[0], acc[1]);
        odw[h * 2 + dt][1] = pack2(acc[2], acc[3]);
      }
    }

    // === attn-out + residual (A = ao_w rows global, B = o^T-built) ===
    {
      bf16x8 Bo[4];
#pragma unroll
      for (int ks = 0; ks < 4; ++ks)
        Bo[ks] = trans2(odw[2 * ks][0], odw[2 * ks][1], odw[2 * ks + 1][0], odw[2 * ks + 1][1], c16, quad);
      const __bf16* aoW = wb + WB_AO + l * 128 * 128;
#pragma unroll
      for (int mt = 0; mt < 8; ++mt) {
        f32x4 acc{0, 0, 0, 0};
#pragma unroll
        for (int ks = 0; ks < 4; ++ks)
          acc = MFMA(ld8(aoW + (mt * 16 + c16) * 128 + ks * 32 + quad * 8), Bo[ks], acc);
        f32x4 bi = *(const f32x4*)(ao_b + l * 128 + mt * 16 + quad * 4);
#pragma unroll
        for (int r = 0; r < 4; ++r) res[mt][r] += acc[r] + bi[r];
      }
    }
    ln_reg(res, ln1_g + l * 128, ln1_b + l * 128, quad);
#pragma unroll
    for (int mt = 0; mt < 8; ++mt) {
      xdw[mt][0] = pack2(res[mt][0], res[mt][1]);
      xdw[mt][1] = pack2(res[mt][2], res[mt][3]);
    }
    __syncthreads();  // all waves done reading Kl/Vl before hl (aliasing) writes

    // === FF1 (relu) -> wave-private LDS slab hl[16][264] in B-operand layout ===
    {
      bf16x8 Bx2[4];
#pragma unroll
      for (int ks = 0; ks < 4; ++ks)
        Bx2[ks] = trans2(xdw[2 * ks][0], xdw[2 * ks][1], xdw[2 * ks + 1][0], xdw[2 * ks + 1][1], c16, quad);
      const __bf16* f1W = wb + WB_FF1 + l * 256 * 128;
#pragma unroll
      for (int half = 0; half < 2; ++half)
#pragma unroll
        for (int mt = 0; mt < 8; ++mt) {
          f32x4 acc{0, 0, 0, 0};
#pragma unroll
          for (int ks = 0; ks < 4; ++ks)
            acc = MFMA(ld8(f1W + (half * 128 + mt * 16 + c16) * 128 + ks * 32 + quad * 8), Bx2[ks], acc);
          f32x4 bi = *(const f32x4*)(ff1_b + l * 256 + half * 128 + mt * 16 + quad * 4);
          bf16x4 pk;
#pragma unroll
          for (int r = 0; r < 4; ++r) pk[r] = (__bf16)fmaxf(acc[r] + bi[r], 0.f);
          // C-frag rows hf = half*128+mt*16+quad*4+r, col = own node (c16)
          *(bf16x4*)(hw + c16 * 264 + half * 128 + mt * 16 + quad * 4) = pk;
        }
    }
    // no barrier: hl slab is wave-private (lgkmcnt ordering within wave suffices)

    // === FF2 + residual: B-frags read straight from hl ===
    {
      const __bf16* f2W = wb + WB_FF2 + l * 128 * 256;
      f32x4 f2a[8];
#pragma unroll
      for (int mt = 0; mt < 8; ++mt) f2a[mt] = f32x4{0, 0, 0, 0};
#pragma unroll
      for (int ks = 0; ks < 8; ++ks) {
        bf16x8 Bh = ld8(hw + c16 * 264 + ks * 32 + quad * 8);
#pragma unroll
        for (int mt = 0; mt < 8; ++mt)
          f2a[mt] = MFMA(ld8(f2W + (mt * 16 + c16) * 256 + ks * 32 + quad * 8), Bh, f2a[mt]);
      }
#pragma unroll
      for (int mt = 0; mt < 8; ++mt) {
        f32x4 bi = *(const f32x4*)(ff2_b + l * 128 + mt * 16 + quad * 4);
#pragma unroll
        for (int r = 0; r < 4; ++r) res[mt][r] += f2a[mt][r] + bi[r];
      }
    }
    ln_reg(res, ln2_g + l * 128, ln2_b + l * 128, quad);
#pragma unroll
    for (int mt = 0; mt < 8; ++mt) {
      xdw[mt][0] = pack2(res[mt][0], res[mt][1]);
      xdw[mt][1] = pack2(res[mt][2], res[mt][3]);
    }
  }

  // ---- stage out: x_final^T frags -> X[f][node][feat] (bf16) ----
  if (node < NN_) {
    __bf16* Xf = Xg + (size_t)f * 5376 + node * 128;
#pragma unroll
    for (int mt = 0; mt < 8; ++mt) {
      int2 v; v.x = xdw[mt][0]; v.y = xdw[mt][1];
      *(int2*)(Xf + mt * 16 + quad * 4) = v;
    }
  }
}

// ---------------- output projection + final LN: 4-way K-split, 4 N-tiles/wave ----------------
__global__ __launch_bounds__(512) void wout_k(const __bf16* __restrict__ X,
                                              const __bf16* __restrict__ Wb,
                                              const float* __restrict__ b_out,
                                              const float* __restrict__ lnf_g,
                                              const float* __restrict__ lnf_b,
                                              float* __restrict__ out) {
  const int blk = blockIdx.x, tid = threadIdx.x;
  const int lane = tid & 63, w2 = tid >> 6;
  const int kq = w2 >> 1, cg = w2 & 1;  // K quarter (1344), column half (64 cols)
  const int c16 = lane & 15, quad = lane >> 4;
  __shared__ float cout[4 * 16 * 132];
  f32x4 acc[4];
#pragma unroll
  for (int nt = 0; nt < 4; ++nt) acc[nt] = f32x4{0, 0, 0, 0};
  const __bf16* Ar = X + (size_t)(blk * 16 + c16) * 5376 + kq * 1344;
  const __bf16* Bp[4];
#pragma unroll
  for (int nt = 0; nt < 4; ++nt)
    Bp[nt] = Wb + (size_t)(cg * 64 + nt * 16 + c16) * 5376 + kq * 1344;
#pragma unroll 2
  for (int ks = 0; ks < 42; ++ks) {
    int ko = ks * 32 + quad * 8;
    bf16x8 a = ld8(Ar + ko);
#pragma unroll
    for (int nt = 0; nt < 4; ++nt) acc[nt] = MFMA(a, ld8(Bp[nt] + ko), acc[nt]);
  }
#pragma unroll
  for (int nt = 0; nt < 4; ++nt)
#pragma unroll
    for (int r = 0; r < 4; ++r)
      cout[(kq * 16 + quad * 4 + r) * 132 + cg * 64 + nt * 16 + c16] = acc[nt][r];
  __syncthreads();
  if (w2 < 4) {
#pragma unroll
    for (int rr = 0; rr < 4; ++rr) {
      int row = w2 * 4 + rr;
      float v0 = b_out[lane], v1 = b_out[64 + lane];
#pragma unroll
      for (int kk = 0; kk < 4; ++kk) {
        v0 += cout[(kk * 16 + row) * 132 + lane];
        v1 += cout[(kk * 16 + row) * 132 + 64 + lane];
      }
      float s = v0 + v1, ss = v0 * v0 + v1 * v1;
#pragma unroll
      for (int m = 1; m < 64; m <<= 1) { s += __shfl_xor(s, m); ss += __shfl_xor(ss, m); }
      float mu = s * 0.0078125f;
      float var = fmaxf(ss * 0.0078125f - mu * mu, 0.f);
      float rs = rsqrtf(var + 1e-5f);
      size_t o = (size_t)(blk * 16 + row) * 128;
      out[o + lane] = (v0 - mu) * rs * lnf_g[lane] + lnf_b[lane];
      out[o + 64 + lane] = (v1 - mu) * rs * lnf_g[64 + lane] + lnf_b[64 + lane];
    }
  }
}

extern "C" void kernel_launch(void* const* d_in, const int* in_sizes, int n_in,
                              void* d_out, int out_size, void* d_ws, size_t ws_size,
                              hipStream_t stream) {
  const float* forest     = (const float*)d_in[0];
  const int*   adjacency  = (const int*)d_in[1];
  const int*   node_order = (const int*)d_in[2];
  const float* W_in       = (const float*)d_in[3];
  const float* b_in       = (const float*)d_in[4];
  const float* qkv_w      = (const float*)d_in[5];
  const float* qkv_b      = (const float*)d_in[6];
  const float* ao_w       = (const float*)d_in[7];
  const float* ao_b       = (const float*)d_in[8];
  const float* ff1_w      = (const float*)d_in[9];
  const float* ff1_b      = (const float*)d_in[10];
  const float* ff2_w      = (const float*)d_in[11];
  const float* ff2_b      = (const float*)d_in[12];
  const float* ln1_g      = (const float*)d_in[13];
  const float* ln1_b      = (const float*)d_in[14];
  const float* ln2_g      = (const float*)d_in[15];
  const float* ln2_b      = (const float*)d_in[16];
  const float* b_out      = (const float*)d_in[18];
  const float* lnf_g      = (const float*)d_in[19];
  const float* lnf_b      = (const float*)d_in[20];
  __bf16* wbp = (__bf16*)d_ws;
  float* out = (float*)d_out;

  prep_bf16<<<dim3(PREP_N / 256), dim3(256), 0, stream>>>(W_in, qkv_w, ao_w, ff1_w, ff2_w,
                                                          (const float*)d_in[17], wbp);
  tree_enc<<<dim3(FB_), dim3(192), 0, stream>>>(forest, adjacency, node_order, b_in, qkv_b, ao_b,
                                                ff1_b, ff2_b, ln1_g, ln1_b, ln2_g, ln2_b, wbp,
                                                wbp + WB_X);
  wout_k<<<dim3(FB_ / 16), dim3(512), 0, stream>>>(wbp + WB_X, wbp + WB_WOUT, b_out, lnf_g, lnf_b,
                                                   out);
}

// Round 8
// 967.830 us; speedup vs baseline: 1.0849x; 1.0849x over previous
//
#include <hip/hip_runtime.h>
#include <hip/hip_bf16.h>

typedef __bf16 bf16x8 __attribute__((ext_vector_type(8)));
typedef __bf16 bf16x4 __attribute__((ext_vector_type(4)));
typedef float  f32x4  __attribute__((ext_vector_type(4)));

#define MFMA(a,b,c) __builtin_amdgcn_mfma_f32_16x16x32_bf16((a),(b),(c),0,0,0)

// problem constants
#define NN_  42
#define E_   41
#define FB_  4096
#define SCALE_ 0.17677669529663687f  // 1/sqrt(32)

// ws layout, element offsets into __bf16* ws (native [out][in] row-major == MFMA A-operand rows)
#define WB_WIN  0         // [128][32]
#define WB_QKV  4096      // [L][384][128]
#define WB_AO   102400    // [L][128][128]
#define WB_FF1  135168    // [L][256][128]
#define WB_FF2  200704    // [L][128][256]
#define WB_WOUT 266240    // [128][5376]
#define WB_X    954368    // [4096][5376] staged x_final (bf16)
#define PREP_N  954368

// smem byte offsets
#define SM_K    0         // K [48][136] bf16 = 13056
#define SM_V    13056     // V^T [128][72] bf16 = 18432 (pad cols 48..63 re-zeroed EVERY layer)
#define SM_ADJ  31488     // int[123]
#define SM_DEP  31984     // int[48]
#define SM_SZ   32176
// aliases over SM_K..: posf f32[48][132] (pre-layer-0 only); hw per-wave slabs
// [16][264] bf16 = 8448 B/wave x3 = 25344 (FF section only; guarded by layer-top +
// post-attention barriers)

// ---------------- weight cast to bf16 ----------------
__global__ void prep_bf16(const float* __restrict__ W_in, const float* __restrict__ qkv_w,
                          const float* __restrict__ ao_w, const float* __restrict__ ff1_w,
                          const float* __restrict__ ff2_w, const float* __restrict__ W_out,
                          __bf16* __restrict__ wb) {
  int i = blockIdx.x * 256 + threadIdx.x;
  float v;
  if      (i < 4096)   v = W_in[i];
  else if (i < 102400) v = qkv_w[i - 4096];
  else if (i < 135168) v = ao_w[i - 102400];
  else if (i < 200704) v = ff1_w[i - 135168];
  else if (i < 266240) v = ff2_w[i - 200704];
  else if (i < 954368) v = W_out[i - 266240];
  else return;
  wb[i] = (__bf16)v;
}

__device__ __forceinline__ bf16x8 ld8(const __bf16* p) { return *(const bf16x8*)p; }

__device__ __forceinline__ int pack2(float a, float b) {
  union { __bf16 h[2]; int i; } u;
  u.h[0] = (__bf16)a; u.h[1] = (__bf16)b;
  return u.i;
}

// C-frag pair (k on rows: lo tile k 0..15, hi tile k 16..31; n on c16, packed reg-pairs as
// dwords lo0/lo1/hi0/hi1) -> B-frag (n=c16, k=quad*8+j).
__device__ __forceinline__ bf16x8 trans2(int lo0, int lo1, int hi0, int hi1, int c16, int quad) {
  int s0 = ((quad & 1) * 2) * 16 + c16, s1 = s0 + 16;
  int a0 = __shfl(lo0, s0), a1 = __shfl(lo1, s0), a2 = __shfl(lo0, s1), a3 = __shfl(lo1, s1);
  int b0 = __shfl(hi0, s0), b1 = __shfl(hi1, s0), b2 = __shfl(hi0, s1), b3 = __shfl(hi1, s1);
  union { int i[4]; bf16x8 v; } u;
  bool hi = quad > 1;
  u.i[0] = hi ? b0 : a0; u.i[1] = hi ? b1 : a1;
  u.i[2] = hi ? b2 : a2; u.i[3] = hi ? b3 : a3;
  return u.v;
}

// wave-private LayerNorm over x^T frags (feature dim on mt/quad/r; node on c16)
__device__ __forceinline__ void ln_reg(float (&res)[8][4], const float* __restrict__ g,
                                       const float* __restrict__ b, int quad) {
  float s = 0.f, ss = 0.f;
#pragma unroll
  for (int mt = 0; mt < 8; ++mt)
#pragma unroll
    for (int r = 0; r < 4; ++r) { float v = res[mt][r]; s += v; ss += v * v; }
  s += __shfl_xor(s, 16); ss += __shfl_xor(ss, 16);
  s += __shfl_xor(s, 32); ss += __shfl_xor(ss, 32);
  float mu = s * 0.0078125f;
  float var = fmaxf(ss * 0.0078125f - mu * mu, 0.f);
  float rs = rsqrtf(var + 1e-5f);
#pragma unroll
  for (int mt = 0; mt < 8; ++mt) {
    f32x4 g4 = *(const f32x4*)(g + mt * 16 + quad * 4);
    f32x4 b4 = *(const f32x4*)(b + mt * 16 + quad * 4);
#pragma unroll
    for (int r = 0; r < 4; ++r) res[mt][r] = (res[mt][r] - mu) * rs * g4[r] + b4[r];
  }
}

// ---------------- per-tree fused encoder: node-partitioned, register-resident x^T ----------------
// amdgpu_waves_per_eu(2,2): pin the occupancy target. launch_bounds' 2nd arg is only a FLOOR —
// with (192,2)/(192,3) the scheduler targeted 2x the floor (128/84 VGPRs = 512/4, 512/6) and
// paid with loop-resident scratch spills (150-680 MB/dispatch HBM writes, R5-R7). min=max=2
// gives the allocator a 256-reg budget and removes the incentive to spill-to-climb.
__global__ __launch_bounds__(192) __attribute__((amdgpu_waves_per_eu(2, 2))) void tree_enc(
    const float* __restrict__ forest, const int* __restrict__ adjacency,
    const int* __restrict__ node_order, const float* __restrict__ b_in,
    const float* __restrict__ qkv_b, const float* __restrict__ ao_b,
    const float* __restrict__ ff1_b, const float* __restrict__ ff2_b,
    const float* __restrict__ ln1_g, const float* __restrict__ ln1_b,
    const float* __restrict__ ln2_g, const float* __restrict__ ln2_b,
    const __bf16* __restrict__ wb, __bf16* __restrict__ Xg) {
  const int f = blockIdx.x, tid = threadIdx.x;
  const int lane = tid & 63, w = tid >> 6, c16 = lane & 15, quad = lane >> 4;
  const int node = w * 16 + c16;               // this lane's node (B-operand n / C col)
  const int nclamp = node < NN_ ? node : NN_ - 1;

  __shared__ alignas(16) unsigned char smem[SM_SZ];
  __bf16* Kl = (__bf16*)(smem + SM_K);         // [48][136]: K[key][feat]
  __bf16* Vl = (__bf16*)(smem + SM_V);         // [128][72]: V^T[d][key]
  float*  posf = (float*)(smem + SM_K);        // [48][132] f32 (aliases; pre-layer-0 only)
  __bf16* hw   = (__bf16*)(smem + (size_t)w * 8448);  // per-wave FF-hidden slab [16][264]
  int*    adj_s = (int*)(smem + SM_ADJ);
  int*    dep_s = (int*)(smem + SM_DEP);

  // ---- init: zero pos, load adjacency, depths ----
  for (int i = tid; i < 48 * 132; i += 192) posf[i] = 0.f;
  if (tid < E_ * 3) adj_s[tid] = adjacency[f * (E_ * 3) + tid];
  if (w == 1) {
    int v = (lane < NN_) ? node_order[f * NN_ + lane] : 0;
    int mx = v;
#pragma unroll
    for (int m = 1; m < 64; m <<= 1) mx = max(mx, __shfl_xor(mx, m));
    if (lane < 48) dep_s[lane] = (lane < NN_) ? (mx - v) : 0;
  }
  __syncthreads();  // B1

  // ---- embed MFMA: x0^T = W_in @ forest_own^T (+ bias); B = forest row of own node ----
  float res[8][4];
  {
    const float* fr = forest + ((size_t)f * NN_ + nclamp) * 32 + quad * 8;
    f32x4 fa = *(const f32x4*)fr;
    f32x4 fb = *(const f32x4*)(fr + 4);
    union { int i[4]; bf16x8 v; } Bf;
    Bf.i[0] = pack2(fa[0], fa[1]); Bf.i[1] = pack2(fa[2], fa[3]);
    Bf.i[2] = pack2(fb[0], fb[1]); Bf.i[3] = pack2(fb[2], fb[3]);
#pragma unroll
    for (int mt = 0; mt < 8; ++mt) {
      bf16x8 a = ld8(wb + WB_WIN + (mt * 16 + c16) * 32 + quad * 8);
      f32x4 z{0, 0, 0, 0};
      f32x4 c = MFMA(a, Bf.v, z);
      f32x4 bi = *(const f32x4*)(b_in + mt * 16 + quad * 4);
#pragma unroll
      for (int r = 0; r < 4; ++r) res[mt][r] = c[r] + bi[r];
    }
  }
  // positional-encoding walk (wave 0; parent idx < child idx in edge order)
  if (w == 0) {
    for (int e = 0; e < E_; ++e) {
      int p = adj_s[e * 3], c = adj_s[e * 3 + 1], s = adj_s[e * 3 + 2];
      if (p >= 0 && c >= 0) {
        int pl = p - f * NN_, cl = c - f * NN_;
        int si = s + 1; si = si < 0 ? 0 : (si > 2 ? 2 : si);
        int idx = dep_s[pl] * 3 + si;
        float a0 = (lane == idx) ? 1.f : 0.f;
        float a1 = (lane + 64 == idx) ? 1.f : 0.f;
        posf[cl * 132 + lane] = posf[pl * 132 + lane] + a0;
        posf[cl * 132 + 64 + lane] = posf[pl * 132 + 64 + lane] + a1;
      }
    }
  }
  __syncthreads();  // B2

  // add pos (read own node's row)
#pragma unroll
  for (int mt = 0; mt < 8; ++mt) {
    f32x4 pv = *(const f32x4*)(posf + node * 132 + mt * 16 + quad * 4);
#pragma unroll
    for (int r = 0; r < 4; ++r) res[mt][r] += pv[r];
  }
  int xdw[8][2];
#pragma unroll
  for (int mt = 0; mt < 8; ++mt) {
    xdw[mt][0] = pack2(res[mt][0], res[mt][1]);
    xdw[mt][1] = pack2(res[mt][2], res[mt][3]);
  }

  // ---- encoder layers ----
  for (int l = 0; l < 2; ++l) {
    __syncthreads();  // layer top: prior readers of pos / K,V / hw done before overwrite

    // zero V^T key-columns 48..63 EVERY layer (hw clobbers rows 0..87 of Vl during FF;
    // PV's second MFMA reads them with P==0 and NaN*0=NaN — R4 lesson).
    {
      int* vz = (int*)Vl;
      for (int i = tid; i < 1024; i += 192) {
        int row = i >> 3, dc = i & 7;
        vz[row * 36 + 24 + dc] = 0;  // bf16 cols 48..63 of each of 128 rows
      }
    }

    const __bf16* Wq = wb + WB_QKV + l * 384 * 128;
    bf16x8 Bx[4];
#pragma unroll
    for (int ks = 0; ks < 4; ++ks)
      Bx[ks] = trans2(xdw[2 * ks][0], xdw[2 * ks][1], xdw[2 * ks + 1][0], xdw[2 * ks + 1][1], c16, quad);

    int qdw[8][2];
    // q-part (rows 0..127): keep in regs (packed)
#pragma unroll
    for (int mt = 0; mt < 8; ++mt) {
      f32x4 acc{0, 0, 0, 0};
#pragma unroll
      for (int ks = 0; ks < 4; ++ks)
        acc = MFMA(ld8(Wq + (mt * 16 + c16) * 128 + ks * 32 + quad * 8), Bx[ks], acc);
      f32x4 bi = *(const f32x4*)(qkv_b + l * 384 + mt * 16 + quad * 4);
      qdw[mt][0] = pack2(acc[0] + bi[0], acc[1] + bi[1]);
      qdw[mt][1] = pack2(acc[2] + bi[2], acc[3] + bi[3]);
    }
    // k-part (rows 128..255) -> K LDS [key][feat]
#pragma unroll
    for (int mt = 0; mt < 8; ++mt) {
      f32x4 acc{0, 0, 0, 0};
#pragma unroll
      for (int ks = 0; ks < 4; ++ks)
        acc = MFMA(ld8(Wq + (128 + mt * 16 + c16) * 128 + ks * 32 + quad * 8), Bx[ks], acc);
      f32x4 bi = *(const f32x4*)(qkv_b + l * 384 + 128 + mt * 16 + quad * 4);
#pragma unroll
      for (int r = 0; r < 4; ++r)
        Kl[node * 136 + mt * 16 + quad * 4 + r] = (__bf16)(acc[r] + bi[r]);
    }
    // v-part (rows 256..383) -> V^T LDS [d][key]
#pragma unroll
    for (int mt = 0; mt < 8; ++mt) {
      f32x4 acc{0, 0, 0, 0};
#pragma unroll
      for (int ks = 0; ks < 4; ++ks)
        acc = MFMA(ld8(Wq + (256 + mt * 16 + c16) * 128 + ks * 32 + quad * 8), Bx[ks], acc);
      f32x4 bi = *(const f32x4*)(qkv_b + l * 384 + 256 + mt * 16 + quad * 4);
#pragma unroll
      for (int r = 0; r < 4; ++r)
        Vl[(mt * 16 + quad * 4 + r) * 72 + node] = (__bf16)(acc[r] + bi[r]);
    }
    __syncthreads();  // K,V visible

    // === attention: all 4 heads, wave-private; PV packs straight to odw ===
    int odw[8][2];
#pragma unroll
    for (int h = 0; h < 4; ++h) {
      bf16x8 Bq = trans2(qdw[2 * h][0], qdw[2 * h][1], qdw[2 * h + 1][0], qdw[2 * h + 1][1], c16, quad);
      f32x4 st[3];
#pragma unroll
      for (int mt = 0; mt < 3; ++mt) {
        f32x4 z{0, 0, 0, 0};
        st[mt] = MFMA(ld8(Kl + (mt * 16 + c16) * 136 + h * 32 + quad * 8), Bq, z);
      }
      float mx = -3.0e38f;
#pragma unroll
      for (int mt = 0; mt < 3; ++mt)
#pragma unroll
        for (int r = 0; r < 4; ++r) {
          float v = st[mt][r] * SCALE_;
          bool valid = (mt < 2) || (quad * 4 + r < 10);  // key < 42
          st[mt][r] = valid ? v : -3.0e38f;
          mx = fmaxf(mx, st[mt][r]);
        }
      mx = fmaxf(mx, __shfl_xor(mx, 16));
      mx = fmaxf(mx, __shfl_xor(mx, 32));
      float sm = 0.f, ev[3][4];
#pragma unroll
      for (int mt = 0; mt < 3; ++mt)
#pragma unroll
        for (int r = 0; r < 4; ++r) { float e = __expf(st[mt][r] - mx); ev[mt][r] = e; sm += e; }
      sm += __shfl_xor(sm, 16);
      sm += __shfl_xor(sm, 32);
      float inv = 1.f / sm;
      int dwp[3][2];
#pragma unroll
      for (int mt = 0; mt < 3; ++mt) {
        dwp[mt][0] = pack2(ev[mt][0] * inv, ev[mt][1] * inv);
        dwp[mt][1] = pack2(ev[mt][2] * inv, ev[mt][3] * inv);
      }
      bf16x8 Bp0 = trans2(dwp[0][0], dwp[0][1], dwp[1][0], dwp[1][1], c16, quad);
      bf16x8 Bp1 = trans2(dwp[2][0], dwp[2][1], 0, 0, c16, quad);
#pragma unroll
      for (int dt = 0; dt < 2; ++dt) {
        f32x4 acc{0, 0, 0, 0};
        acc = MFMA(ld8(Vl + (h * 32 + dt * 16 + c16) * 72 + quad * 8), Bp0, acc);
        acc = MFMA(ld8(Vl + (h * 32 + dt * 16 + c16) * 72 + 32 + quad * 8), Bp1, acc);
        odw[h * 2 + dt][0] = pack2(acc[0], acc[1]);
        odw[h * 2 + dt][1] = pack2(acc[2], acc[3]);
      }
    }

    // === attn-out + residual (A = ao_w rows global, B = o^T-built) ===
    {
      bf16x8 Bo[4];
#pragma unroll
      for (int ks = 0; ks < 4; ++ks)
        Bo[ks] = trans2(odw[2 * ks][0], odw[2 * ks][1], odw[2 * ks + 1][0], odw[2 * ks + 1][1], c16, quad);
      const __bf16* aoW = wb + WB_AO + l * 128 * 128;
#pragma unroll
      for (int mt = 0; mt < 8; ++mt) {
        f32x4 acc{0, 0, 0, 0};
#pragma unroll
        for (int ks = 0; ks < 4; ++ks)
          acc = MFMA(ld8(aoW + (mt * 16 + c16) * 128 + ks * 32 + quad * 8), Bo[ks], acc);
        f32x4 bi = *(const f32x4*)(ao_b + l * 128 + mt * 16 + quad * 4);
#pragma unroll
        for (int r = 0; r < 4; ++r) res[mt][r] += acc[r] + bi[r];
      }
    }
    ln_reg(res, ln1_g + l * 128, ln1_b + l * 128, quad);
#pragma unroll
    for (int mt = 0; mt < 8; ++mt) {
      xdw[mt][0] = pack2(res[mt][0], res[mt][1]);
      xdw[mt][1] = pack2(res[mt][2], res[mt][3]);
    }
    __syncthreads();  // all waves done reading Kl/Vl before hw (aliasing) writes

    // === FF1 (relu) -> wave-private LDS slab hw[16][264] in B-operand layout ===
    {
      bf16x8 Bx2[4];
#pragma unroll
      for (int ks = 0; ks < 4; ++ks)
        Bx2[ks] = trans2(xdw[2 * ks][0], xdw[2 * ks][1], xdw[2 * ks + 1][0], xdw[2 * ks + 1][1], c16, quad);
      const __bf16* f1W = wb + WB_FF1 + l * 256 * 128;
#pragma unroll
      for (int half = 0; half < 2; ++half)
#pragma unroll
        for (int mt = 0; mt < 8; ++mt) {
          f32x4 acc{0, 0, 0, 0};
#pragma unroll
          for (int ks = 0; ks < 4; ++ks)
            acc = MFMA(ld8(f1W + (half * 128 + mt * 16 + c16) * 128 + ks * 32 + quad * 8), Bx2[ks], acc);
          f32x4 bi = *(const f32x4*)(ff1_b + l * 256 + half * 128 + mt * 16 + quad * 4);
          bf16x4 pk;
#pragma unroll
          for (int r = 0; r < 4; ++r) pk[r] = (__bf16)fmaxf(acc[r] + bi[r], 0.f);
          *(bf16x4*)(hw + c16 * 264 + half * 128 + mt * 16 + quad * 4) = pk;
        }
    }
    // no barrier: hw slab is wave-private (lgkmcnt ordering within wave suffices)

    // === FF2 + residual: B-frags read straight from hw ===
    {
      const __bf16* f2W = wb + WB_FF2 + l * 128 * 256;
      f32x4 f2a[8];
#pragma unroll
      for (int mt = 0; mt < 8; ++mt) f2a[mt] = f32x4{0, 0, 0, 0};
#pragma unroll
      for (int ks = 0; ks < 8; ++ks) {
        bf16x8 Bh = ld8(hw + c16 * 264 + ks * 32 + quad * 8);
#pragma unroll
        for (int mt = 0; mt < 8; ++mt)
          f2a[mt] = MFMA(ld8(f2W + (mt * 16 + c16) * 256 + ks * 32 + quad * 8), Bh, f2a[mt]);
      }
#pragma unroll
      for (int mt = 0; mt < 8; ++mt) {
        f32x4 bi = *(const f32x4*)(ff2_b + l * 128 + mt * 16 + quad * 4);
#pragma unroll
        for (int r = 0; r < 4; ++r) res[mt][r] += f2a[mt][r] + bi[r];
      }
    }
    ln_reg(res, ln2_g + l * 128, ln2_b + l * 128, quad);
#pragma unroll
    for (int mt = 0; mt < 8; ++mt) {
      xdw[mt][0] = pack2(res[mt][0], res[mt][1]);
      xdw[mt][1] = pack2(res[mt][2], res[mt][3]);
    }
  }

  // ---- stage out: x_final^T frags -> X[f][node][feat] (bf16) ----
  if (node < NN_) {
    __bf16* Xf = Xg + (size_t)f * 5376 + node * 128;
#pragma unroll
    for (int mt = 0; mt < 8; ++mt) {
      int2 v; v.x = xdw[mt][0]; v.y = xdw[mt][1];
      *(int2*)(Xf + mt * 16 + quad * 4) = v;
    }
  }
}

// ---------------- output projection + final LN: 4-way K-split, 4 N-tiles/wave ----------------
__global__ __launch_bounds__(512) void wout_k(const __bf16* __restrict__ X,
                                              const __bf16* __restrict__ Wb,
                                              const float* __restrict__ b_out,
                                              const float* __restrict__ lnf_g,
                                              const float* __restrict__ lnf_b,
                                              float* __restrict__ out) {
  const int blk = blockIdx.x, tid = threadIdx.x;
  const int lane = tid & 63, w2 = tid >> 6;
  const int kq = w2 >> 1, cg = w2 & 1;  // K quarter (1344), column half (64 cols)
  const int c16 = lane & 15, quad = lane >> 4;
  __shared__ float cout[4 * 16 * 132];
  f32x4 acc[4];
#pragma unroll
  for (int nt = 0; nt < 4; ++nt) acc[nt] = f32x4{0, 0, 0, 0};
  const __bf16* Ar = X + (size_t)(blk * 16 + c16) * 5376 + kq * 1344;
  const __bf16* Bp[4];
#pragma unroll
  for (int nt = 0; nt < 4; ++nt)
    Bp[nt] = Wb + (size_t)(cg * 64 + nt * 16 + c16) * 5376 + kq * 1344;
#pragma unroll 2
  for (int ks = 0; ks < 42; ++ks) {
    int ko = ks * 32 + quad * 8;
    bf16x8 a = ld8(Ar + ko);
#pragma unroll
    for (int nt = 0; nt < 4; ++nt) acc[nt] = MFMA(a, ld8(Bp[nt] + ko), acc[nt]);
  }
#pragma unroll
  for (int nt = 0; nt < 4; ++nt)
#pragma unroll
    for (int r = 0; r < 4; ++r)
      cout[(kq * 16 + quad * 4 + r) * 132 + cg * 64 + nt * 16 + c16] = acc[nt][r];
  __syncthreads();
  if (w2 < 4) {
#pragma unroll
    for (int rr = 0; rr < 4; ++rr) {
      int row = w2 * 4 + rr;
      float v0 = b_out[lane], v1 = b_out[64 + lane];
#pragma unroll
      for (int kk = 0; kk < 4; ++kk) {
        v0 += cout[(kk * 16 + row) * 132 + lane];
        v1 += cout[(kk * 16 + row) * 132 + 64 + lane];
      }
      float s = v0 + v1, ss = v0 * v0 + v1 * v1;
#pragma unroll
      for (int m = 1; m < 64; m <<= 1) { s += __shfl_xor(s, m); ss += __shfl_xor(ss, m); }
      float mu = s * 0.0078125f;
      float var = fmaxf(ss * 0.0078125f - mu * mu, 0.f);
      float rs = rsqrtf(var + 1e-5f);
      size_t o = (size_t)(blk * 16 + row) * 128;
      out[o + lane] = (v0 - mu) * rs * lnf_g[lane] + lnf_b[lane];
      out[o + 64 + lane] = (v1 - mu) * rs * lnf_g[64 + lane] + lnf_b[64 + lane];
    }
  }
}

extern "C" void kernel_launch(void* const* d_in, const int* in_sizes, int n_in,
                              void* d_out, int out_size, void* d_ws, size_t ws_size,
                              hipStream_t stream) {
  const float* forest     = (const float*)d_in[0];
  const int*   adjacency  = (const int*)d_in[1];
  const int*   node_order = (const int*)d_in[2];
  const float* W_in       = (const float*)d_in[3];
  const float* b_in       = (const float*)d_in[4];
  const float* qkv_w      = (const float*)d_in[5];
  const float* qkv_b      = (const float*)d_in[6];
  const float* ao_w       = (const float*)d_in[7];
  const float* ao_b       = (const float*)d_in[8];
  const float* ff1_w      = (const float*)d_in[9];
  const float* ff1_b      = (const float*)d_in[10];
  const float* ff2_w      = (const float*)d_in[11];
  const float* ff2_b      = (const float*)d_in[12];
  const float* ln1_g      = (const float*)d_in[13];
  const float* ln1_b      = (const float*)d_in[14];
  const float* ln2_g      = (const float*)d_in[15];
  const float* ln2_b      = (const float*)d_in[16];
  const float* b_out      = (const float*)d_in[18];
  const float* lnf_g      = (const float*)d_in[19];
  const float* lnf_b      = (const float*)d_in[20];
  __bf16* wbp = (__bf16*)d_ws;
  float* out = (float*)d_out;

  prep_bf16<<<dim3(PREP_N / 256), dim3(256), 0, stream>>>(W_in, qkv_w, ao_w, ff1_w, ff2_w,
                                                          (const float*)d_in[17], wbp);
  tree_enc<<<dim3(FB_), dim3(192), 0, stream>>>(forest, adjacency, node_order, b_in, qkv_b, ao_b,
                                                ff1_b, ff2_b, ln1_g, ln1_b, ln2_g, ln2_b, wbp,
                                                wbp + WB_X);
  wout_k<<<dim3(FB_ / 16), dim3(512), 0, stream>>>(wbp + WB_X, wbp + WB_WOUT, b_out, lnf_g, lnf_b,
                                                   out);
}